// Round 7
// baseline (511.012 us; speedup 1.0000x reference)
//
#include <hip/hip_runtime.h>
#include <hip/hip_bf16.h>
#include <math.h>

#define S_LEN 2048
#define DM 1024
#define NH 16
#define DK 64

typedef short s8v __attribute__((ext_vector_type(8)));   // 8 bf16 (A/B frag, 4 VGPR)
typedef float f4v __attribute__((ext_vector_type(4)));   // 4 f32  (C/D frag)

__device__ inline ushort bf16_rn(float v) {
    unsigned u = __float_as_uint(v);
    u += 0x7FFFu + ((u >> 16) & 1u);
    return (ushort)(u >> 16);
}
__device__ inline float bf16f(ushort h) { return __uint_as_float(((unsigned)h) << 16); }

// pack 2 fp32 -> u32 of 2 bf16 (RNE, v_cvt_pk path) + residuals
__device__ inline uint packpair(float a, float b, float& ra, float& rb) {
    union { __hip_bfloat162 h; uint u; } cv;
    cv.h = __float22bfloat162_rn(make_float2(a, b));
    ra = a - __uint_as_float(cv.u << 16);
    rb = b - __uint_as_float(cv.u & 0xffff0000u);
    return cv.u;
}
__device__ inline uint packonly(float a, float b) {
    union { __hip_bfloat162 h; uint u; } cv;
    cv.h = __float22bfloat162_rn(make_float2(a, b));
    return cv.u;
}

// ---------------------------------------------------------------------------
// Pre-split fp32 -> bf16 hi + lo residual for x and the 4 weight matrices.
// ---------------------------------------------------------------------------
__global__ __launch_bounds__(256) void convert_kernel(
    const float* __restrict__ x,
    const float* __restrict__ Wq, const float* __restrict__ Wk,
    const float* __restrict__ Wv, const float* __restrict__ Wo,
    ushort* __restrict__ xh, ushort* __restrict__ xl,
    ushort* __restrict__ wh, ushort* __restrict__ wl)
{
    long idx = (long)blockIdx.x * 256 + threadIdx.x;    // 2M float4 groups
    const float4* src;
    ushort* dh; ushort* dl; long off;
    if (idx < 1048576) {                                 // x: 4M elems
        src = (const float4*)x; off = idx; dh = xh; dl = xl;
    } else {
        long wi = idx - 1048576;
        int which = (int)(wi >> 18);                     // 262144 groups per W
        const float* wp = which == 0 ? Wq : which == 1 ? Wk : which == 2 ? Wv : Wo;
        src = (const float4*)wp; off = wi & 262143;
        dh = wh + (long)which * 1048576;
        dl = wl + (long)which * 1048576;
    }
    float4 v = src[off];
    ushort4 hv, lv;
    hv.x = bf16_rn(v.x); lv.x = bf16_rn(v.x - bf16f(hv.x));
    hv.y = bf16_rn(v.y); lv.y = bf16_rn(v.y - bf16f(hv.y));
    hv.z = bf16_rn(v.z); lv.z = bf16_rn(v.z - bf16f(hv.z));
    hv.w = bf16_rn(v.w); lv.w = bf16_rn(v.w - bf16f(hv.w));
    ((ushort4*)dh)[off] = hv;
    ((ushort4*)dl)[off] = lv;
}

// ---------------------------------------------------------------------------
// RoPE cos/sin table
// ---------------------------------------------------------------------------
__global__ __launch_bounds__(256) void rope_table_kernel(float* __restrict__ tab) {
    int idx = blockIdx.x * 256 + threadIdx.x;
    if (idx >= S_LEN * 32) return;
    int p = idx >> 5, i = idx & 31;
    float invf = powf(10000.0f, -(float)(2 * i) / 64.0f);
    float ang = (float)p * invf;
    tab[idx * 2 + 0] = cosf(ang);
    tab[idx * 2 + 1] = sinf(ang);
}

// ---------------------------------------------------------------------------
// Split-bf16 MFMA GEMM on pre-split inputs (unchanged from round 5).
// ---------------------------------------------------------------------------
template <int MODE>
__global__ __launch_bounds__(256, 2) void mfma_gemm(
    const ushort* __restrict__ Ah_g, const ushort* __restrict__ Al_g,
    const ushort* __restrict__ Wh_g, const ushort* __restrict__ Wl_g,
    const float* __restrict__ b0, const float* __restrict__ b1, const float* __restrict__ b2,
    const float* __restrict__ rope_tab, const int* __restrict__ tokpos,
    ushort* __restrict__ qh, ushort* __restrict__ ql,
    ushort* __restrict__ kh, ushort* __restrict__ kl,
    ushort* __restrict__ vh, ushort* __restrict__ vl,
    float* __restrict__ out)
{
    const int m0 = blockIdx.x * 128;
    const int n0 = blockIdx.y * 64;
    const int which = (MODE == 0) ? blockIdx.z : 0;
    const ushort* WhP = Wh_g + (long)(MODE == 0 ? which : 3) * 1048576;
    const ushort* WlP = Wl_g + (long)(MODE == 0 ? which : 3) * 1048576;
    const float* bias = (which == 0) ? b0 : (which == 1) ? b1 : b2;

    __shared__ ushort Ah[128 * 64], Al[128 * 64];
    __shared__ ushort Bh[64 * 64],  Bl[64 * 64];

    const int t = threadIdx.x;
    const int w = t >> 6, l = t & 63, g = l >> 4, c = l & 15;
    const int wm = w >> 1, wn = w & 1;

    const int rA2 = t >> 1;
    const int kh0 = (t & 1) * 32;
    const int rW  = t >> 2;
    const int kq0 = (t & 3) * 16;

    f4v acc[4][2];
#pragma unroll
    for (int i = 0; i < 4; ++i)
#pragma unroll
        for (int j = 0; j < 2; ++j) acc[i][j] = (f4v){0.f, 0.f, 0.f, 0.f};

    const ushort* ApH = Ah_g + (long)(m0 + rA2) * DM + kh0;
    const ushort* ApL = Al_g + (long)(m0 + rA2) * DM + kh0;
    const ushort* WpH = WhP + (long)(n0 + rW) * DM + kq0;
    const ushort* WpL = WlP + (long)(n0 + rW) * DM + kq0;

    s8v pah[4], pal[4], pwh[2], pwl[2];
#pragma unroll
    for (int q = 0; q < 4; ++q) {
        pah[q] = *(const s8v*)(ApH + q * 8);
        pal[q] = *(const s8v*)(ApL + q * 8);
    }
#pragma unroll
    for (int q = 0; q < 2; ++q) {
        pwh[q] = *(const s8v*)(WpH + q * 8);
        pwl[q] = *(const s8v*)(WpL + q * 8);
    }

    for (int ch = 0; ch < 16; ++ch) {
        __syncthreads();
#pragma unroll
        for (int q = 0; q < 4; ++q) {
            const int b = (kh0 >> 3) + q;
            const int sb = (b ^ (rA2 & 7)) * 8;
            *(s8v*)&Ah[rA2 * 64 + sb] = pah[q];
            *(s8v*)&Al[rA2 * 64 + sb] = pal[q];
        }
#pragma unroll
        for (int q = 0; q < 2; ++q) {
            const int b = (kq0 >> 3) + q;
            const int sb = (b ^ (rW & 7)) * 8;
            *(s8v*)&Bh[rW * 64 + sb] = pwh[q];
            *(s8v*)&Bl[rW * 64 + sb] = pwl[q];
        }
        __syncthreads();

        if (ch + 1 < 16) {
            const int k0 = (ch + 1) * 64;
#pragma unroll
            for (int q = 0; q < 4; ++q) {
                pah[q] = *(const s8v*)(ApH + k0 + q * 8);
                pal[q] = *(const s8v*)(ApL + k0 + q * 8);
            }
#pragma unroll
            for (int q = 0; q < 2; ++q) {
                pwh[q] = *(const s8v*)(WpH + k0 + q * 8);
                pwl[q] = *(const s8v*)(WpL + k0 + q * 8);
            }
        }

#pragma unroll
        for (int kc = 0; kc < 2; ++kc) {
            const int blk = ((kc * 4 + g) ^ (c & 7)) * 8;
            s8v afh[4], afl[4], bfh[2], bfl[2];
#pragma unroll
            for (int mf = 0; mf < 4; ++mf) {
                const int row = wm * 64 + mf * 16 + c;
                afh[mf] = *(const s8v*)&Ah[row * 64 + blk];
                afl[mf] = *(const s8v*)&Al[row * 64 + blk];
            }
#pragma unroll
            for (int nf = 0; nf < 2; ++nf) {
                const int row = wn * 32 + nf * 16 + c;
                bfh[nf] = *(const s8v*)&Bh[row * 64 + blk];
                bfl[nf] = *(const s8v*)&Bl[row * 64 + blk];
            }
#pragma unroll
            for (int mf = 0; mf < 4; ++mf)
#pragma unroll
                for (int nf = 0; nf < 2; ++nf) {
                    acc[mf][nf] = __builtin_amdgcn_mfma_f32_16x16x32_bf16(afh[mf], bfh[nf], acc[mf][nf], 0, 0, 0);
                    acc[mf][nf] = __builtin_amdgcn_mfma_f32_16x16x32_bf16(afh[mf], bfl[nf], acc[mf][nf], 0, 0, 0);
                    acc[mf][nf] = __builtin_amdgcn_mfma_f32_16x16x32_bf16(afl[mf], bfh[nf], acc[mf][nf], 0, 0, 0);
                }
        }
    }

#pragma unroll
    for (int nf = 0; nf < 2; ++nf) {
        const int ecol = n0 + wn * 32 + nf * 16 + c;
        const float bv = bias[ecol];
        if (MODE == 1) {
#pragma unroll
            for (int mf = 0; mf < 4; ++mf)
#pragma unroll
                for (int r = 0; r < 4; ++r) {
                    const int m = m0 + wm * 64 + mf * 16 + 4 * g + r;
                    out[(long)m * DM + ecol] = acc[mf][nf][r] + bv;
                }
        } else {
            const int hH = ecol >> 6, dk = ecol & 63, fi = dk >> 1;
            ushort* dh = (which == 0) ? qh : (which == 1) ? kh : vh;
            ushort* dl = (which == 0) ? ql : (which == 1) ? kl : vl;
#pragma unroll
            for (int mf = 0; mf < 4; ++mf)
#pragma unroll
                for (int r = 0; r < 4; ++r) {
                    const int m = m0 + wm * 64 + mf * 16 + 4 * g + r;
                    const float val = acc[mf][nf][r] + bv;
                    const float par = __shfl_xor(val, 1);
                    float vr;
                    if (which == 2) {
                        vr = val;
                    } else {
                        const int pos = tokpos[m];
                        const float2 cs = ((const float2*)rope_tab)[pos * 32 + fi];
                        vr = (c & 1) ? fmaf(par, cs.y, val * cs.x)
                                     : fmaf(val, cs.x, -par * cs.y);
                    }
                    const ushort hh = bf16_rn(vr);
                    const ushort ll = bf16_rn(vr - bf16f(hh));
                    const long base = ((long)((m >> 11) * NH + hH) * S_LEN + (m & (S_LEN - 1))) * DK + dk;
                    dh[base] = hh;
                    dl[base] = ll;
                }
        }
    }
}

// ---------------------------------------------------------------------------
// Split-bf16 MFMA flash attention, causal, swapped QK^T, BALANCED Q-PAIRING.
// Block p = blockIdx.x>>1, half = blockIdx.x&1:
//   qf=1 (heavy): q-tile 15-p, rows half*64 + w*16
//   qf=0 (light): q-tile p,    rows half*64 + w*16
// Per-block tiles = 2*(15-p)+half+1; light qf masks itself out beyond its
// causal range -> per-block cost nearly uniform (1.2x spread vs 1.9x before).
// qf processed SERIALLY through one shared P buffer (wave-private, LDS ops
// in-order within a wave -> no barriers): SM(qf)->Pwrite(qf)->PV(qf).
// P rows padded to 68 u32 (bank rotation); packing via v_cvt_pk_bf16_f32
// (__float22bfloat162_rn). K/V layouts unchanged (proven conflict-free).
// LDS = 32KB (K/V) + 17.4KB (P) -> 3 blocks/CU.
// ---------------------------------------------------------------------------
__global__ __launch_bounds__(256, 3) void flash_kernel(
    const ushort* __restrict__ qh_g, const ushort* __restrict__ ql_g,
    const ushort* __restrict__ kh_g, const ushort* __restrict__ kl_g,
    const ushort* __restrict__ vh_g, const ushort* __restrict__ vl_g,
    ushort* __restrict__ ah_g, ushort* __restrict__ al_g)
{
    const int bh = blockIdx.y;
    const int p_ = (int)blockIdx.x >> 1;
    const int half = (int)blockIdx.x & 1;
    const int qb_hi = 15 - p_;
    const int qb_lo = p_;
    const int t = threadIdx.x;
    const int w = t >> 6, l = t & 63, g = l >> 4, c = l & 15;
    const int h = bh & (NH - 1), b_idx = bh >> 4;

    int qbase[2];
    qbase[0] = qb_lo * 128 + half * 64 + w * 16;
    qbase[1] = qb_hi * 128 + half * 64 + w * 16;
    const int ntiles = qb_hi * 2 + half + 1;

    __shared__ ushort Kh[64 * 64], Kl[64 * 64];   // [kv][d] swizzled, 8KB each
    __shared__ ushort Vh[64 * 64], Vl[64 * 64];   // [d][kv] swizzled
    __shared__ uint P_[4 * 1088];                  // per-wave [q16][68 u32]
    uint* Pq = P_ + w * 1088 + c * 68;            // packing rows (q = c)

    // Q B-frags (col=q=c, k=d)
    s8v qhf[2][2], qlf[2][2];
#pragma unroll
    for (int qf = 0; qf < 2; ++qf)
#pragma unroll
        for (int kc = 0; kc < 2; ++kc) {
            const long base = ((long)bh * S_LEN + qbase[qf] + c) * DK + kc * 32 + g * 8;
            qhf[qf][kc] = *(const s8v*)(qh_g + base);
            qlf[qf][kc] = *(const s8v*)(ql_g + base);
        }

    f4v o[2][4];
#pragma unroll
    for (int qf = 0; qf < 2; ++qf)
#pragma unroll
        for (int nt = 0; nt < 4; ++nt) o[qf][nt] = (f4v){0.f, 0.f, 0.f, 0.f};
    float m_[2] = {-INFINITY, -INFINITY};
    float l_[2] = {0.f, 0.f};

    // register prefetch of tile 0
    s8v pkh[2], pkl[2], pvh[2], pvl[2];
    {
        const long rb = ((long)bh * S_LEN + l) * DK;
#pragma unroll
        for (int ib = 0; ib < 2; ++ib) {
            const int b = w + ib * 4;
            pkh[ib] = *(const s8v*)(kh_g + rb + b * 8);
            pkl[ib] = *(const s8v*)(kl_g + rb + b * 8);
            pvh[ib] = *(const s8v*)(vh_g + rb + b * 8);
            pvl[ib] = *(const s8v*)(vl_g + rb + b * 8);
        }
    }

    for (int tile = 0; tile < ntiles; ++tile) {
        __syncthreads();

        // ---- commit K (b128) + V transposed (lane-pair b32) ----
#pragma unroll
        for (int ib = 0; ib < 2; ++ib) {
            const int b = w + ib * 4;
            const int sb = b ^ (l & 7);
            *(s8v*)&Kh[l * 64 + sb * 8] = pkh[ib];
            *(s8v*)&Kl[l * 64 + sb * 8] = pkl[ib];

            uint4 uh = *(uint4*)&pvh[ib];
            uint4 ul = *(uint4*)&pvl[ib];
            uint4 ph_, pl_;
            ph_.x = (uint)__shfl_xor((int)uh.x, 1); ph_.y = (uint)__shfl_xor((int)uh.y, 1);
            ph_.z = (uint)__shfl_xor((int)uh.z, 1); ph_.w = (uint)__shfl_xor((int)uh.w, 1);
            pl_.x = (uint)__shfl_xor((int)ul.x, 1); pl_.y = (uint)__shfl_xor((int)ul.y, 1);
            pl_.z = (uint)__shfl_xor((int)ul.z, 1); pl_.w = (uint)__shfl_xor((int)ul.w, 1);
            const int colp = l & ~1;
            const int odd  = l & 1;
#pragma unroll
            for (int j = 0; j < 4; ++j) {
                const ushort oj   = ((const ushort*)&uh)[j];
                const ushort oj4  = ((const ushort*)&uh)[j + 4];
                const ushort pj   = ((const ushort*)&ph_)[j];
                const ushort pj4  = ((const ushort*)&ph_)[j + 4];
                const ushort loj  = ((const ushort*)&ul)[j];
                const ushort loj4 = ((const ushort*)&ul)[j + 4];
                const ushort plj  = ((const ushort*)&pl_)[j];
                const ushort plj4 = ((const ushort*)&pl_)[j + 4];
                const int d   = b * 8 + (odd ? 4 + j : j);
                const uint hv = odd ? ((uint)pj4  | ((uint)oj4  << 16))
                                    : ((uint)oj   | ((uint)pj   << 16));
                const uint lv = odd ? ((uint)plj4 | ((uint)loj4 << 16))
                                    : ((uint)loj  | ((uint)plj  << 16));
                const int sc2 = (colp >> 3) ^ (d & 7);
                *(uint*)&Vh[d * 64 + sc2 * 8 + (colp & 7)] = hv;
                *(uint*)&Vl[d * 64 + sc2 * 8 + (colp & 7)] = lv;
            }
        }
        __syncthreads();

        // ---- prefetch next tile ----
        if (tile + 1 < ntiles) {
            const long rb = ((long)bh * S_LEN + (tile + 1) * 64 + l) * DK;
#pragma unroll
            for (int ib = 0; ib < 2; ++ib) {
                const int b = w + ib * 4;
                pkh[ib] = *(const s8v*)(kh_g + rb + b * 8);
                pkl[ib] = *(const s8v*)(kl_g + rb + b * 8);
                pvh[ib] = *(const s8v*)(vh_g + rb + b * 8);
                pvl[ib] = *(const s8v*)(vl_g + rb + b * 8);
            }
        }

        const int kvbase = tile * 64;
        int nt_hi[2];
#pragma unroll
        for (int qf = 0; qf < 2; ++qf) {
            const int lim = qbase[qf] + 15 - kvbase;
            int v = lim < 0 ? 0 : (lim >> 4) + 1;
            nt_hi[qf] = v > 4 ? 4 : v;
        }

        // ---- S^T = K * Q^T (3-pass split); K-frag shared across qf ----
        f4v sc[2][4];
#pragma unroll
        for (int qf = 0; qf < 2; ++qf)
#pragma unroll
            for (int nt = 0; nt < 4; ++nt) sc[qf][nt] = (f4v){0.f, 0.f, 0.f, 0.f};
#pragma unroll
        for (int nt = 0; nt < 4; ++nt) {
            if (nt >= nt_hi[1]) continue;
            const int kvl = nt * 16 + c;
#pragma unroll
            for (int kc = 0; kc < 2; ++kc) {
                const int blk = ((kc * 4 + g) ^ (c & 7)) * 8;
                s8v kfh = *(const s8v*)&Kh[kvl * 64 + blk];
                s8v kfl = *(const s8v*)&Kl[kvl * 64 + blk];
#pragma unroll
                for (int qf = 0; qf < 2; ++qf) {
                    if (nt >= nt_hi[qf]) continue;
                    sc[qf][nt] = __builtin_amdgcn_mfma_f32_16x16x32_bf16(kfh, qhf[qf][kc], sc[qf][nt], 0, 0, 0);
                    sc[qf][nt] = __builtin_amdgcn_mfma_f32_16x16x32_bf16(kfh, qlf[qf][kc], sc[qf][nt], 0, 0, 0);
                    sc[qf][nt] = __builtin_amdgcn_mfma_f32_16x16x32_bf16(kfl, qhf[qf][kc], sc[qf][nt], 0, 0, 0);
                }
            }
        }

        // ---- per qf: softmax -> packed P write -> PV (serial, shared P) ----
#pragma unroll
        for (int qf = 0; qf < 2; ++qf) {
            if (nt_hi[qf] == 0) continue;
            const bool needMask = (kvbase + 63) > qbase[qf];
            float s_[4][4];
#pragma unroll
            for (int nt = 0; nt < 4; ++nt)
#pragma unroll
                for (int r = 0; r < 4; ++r) {
                    const float v = sc[qf][nt][r] * 0.125f;
                    const bool bad = (nt >= nt_hi[qf]) ||
                        (needMask && (kvbase + 16 * nt + 4 * g + r > qbase[qf] + c));
                    s_[nt][r] = bad ? -INFINITY : v;
                }
            float tm = -INFINITY;
#pragma unroll
            for (int nt = 0; nt < 4; ++nt)
#pragma unroll
                for (int r = 0; r < 4; ++r) tm = fmaxf(tm, s_[nt][r]);
            tm = fmaxf(tm, __shfl_xor(tm, 16));
            tm = fmaxf(tm, __shfl_xor(tm, 32));
            const float mnew = fmaxf(m_[qf], tm);
            const float corr = __expf(m_[qf] - mnew);
            float psum = 0.f;
#pragma unroll
            for (int nt = 0; nt < 4; ++nt) {
                const float p0 = __expf(s_[nt][0] - mnew);
                const float p1 = __expf(s_[nt][1] - mnew);
                const float p2 = __expf(s_[nt][2] - mnew);
                const float p3 = __expf(s_[nt][3] - mnew);
                psum += (p0 + p1) + (p2 + p3);
                float r0, r1, r2, r3;
                uint2 hw, lw;
                hw.x = packpair(p0, p1, r0, r1);
                hw.y = packpair(p2, p3, r2, r3);
                lw.x = packonly(r0, r1);
                lw.y = packonly(r2, r3);
                const int u0 = ((2 * nt + (g >> 1)) ^ (c & 7)) * 4 + 2 * (g & 1);
                *(uint2*)(Pq + u0) = hw;
                *(uint2*)(Pq + 32 + u0) = lw;
            }
            psum += __shfl_xor(psum, 16);
            psum += __shfl_xor(psum, 32);
            l_[qf] = l_[qf] * corr + psum;
            m_[qf] = mnew;
            // redistribute corr to O-row holders (row q = 4g+r)
            float cD0 = __shfl(corr, (l & 48) + 4 * g + 0);
            float cD1 = __shfl(corr, (l & 48) + 4 * g + 1);
            float cD2 = __shfl(corr, (l & 48) + 4 * g + 2);
            float cD3 = __shfl(corr, (l & 48) + 4 * g + 3);
#pragma unroll
            for (int nt = 0; nt < 4; ++nt) {
                o[qf][nt][0] *= cD0; o[qf][nt][1] *= cD1;
                o[qf][nt][2] *= cD2; o[qf][nt][3] *= cD3;
            }

            // ---- PV for this qf (wave-private P; LDS in-order, no barrier) ----
#pragma unroll
            for (int kc = 0; kc < 2; ++kc) {
                if (nt_hi[qf] <= kc * 2) continue;
                const int pswz = ((4 * kc + g) ^ (c & 7)) * 4;
                s8v pah = *(const s8v*)(Pq + pswz);
                s8v pal = *(const s8v*)(Pq + 32 + pswz);
#pragma unroll
                for (int nt = 0; nt < 4; ++nt) {
                    const int dcol = nt * 16 + c;
                    const int vblk = ((kc * 4 + g) ^ (c & 7)) * 8;
                    s8v vfh = *(const s8v*)&Vh[dcol * 64 + vblk];
                    s8v vfl = *(const s8v*)&Vl[dcol * 64 + vblk];
                    o[qf][nt] = __builtin_amdgcn_mfma_f32_16x16x32_bf16(pah, vfh, o[qf][nt], 0, 0, 0);
                    o[qf][nt] = __builtin_amdgcn_mfma_f32_16x16x32_bf16(pah, vfl, o[qf][nt], 0, 0, 0);
                    o[qf][nt] = __builtin_amdgcn_mfma_f32_16x16x32_bf16(pal, vfh, o[qf][nt], 0, 0, 0);
                }
            }
        }
    }

    // ---- epilogue: normalize (inv redistributed), split-store bf16 hi/lo ----
#pragma unroll
    for (int qf = 0; qf < 2; ++qf) {
        const float inv = 1.0f / l_[qf];
        float iD0 = __shfl(inv, (l & 48) + 4 * g + 0);
        float iD1 = __shfl(inv, (l & 48) + 4 * g + 1);
        float iD2 = __shfl(inv, (l & 48) + 4 * g + 2);
        float iD3 = __shfl(inv, (l & 48) + 4 * g + 3);
#pragma unroll
        for (int nt = 0; nt < 4; ++nt) {
            float vv[4];
            vv[0] = o[qf][nt][0] * iD0;
            vv[1] = o[qf][nt][1] * iD1;
            vv[2] = o[qf][nt][2] * iD2;
            vv[3] = o[qf][nt][3] * iD3;
            const long row0 = (long)b_idx * S_LEN + qbase[qf] + 4 * g;
            const long col = h * DK + nt * 16 + c;
#pragma unroll
            for (int r = 0; r < 4; ++r) {
                const ushort hh = bf16_rn(vv[r]);
                const ushort ll = bf16_rn(vv[r] - bf16f(hh));
                ah_g[(row0 + r) * DM + col] = hh;
                al_g[(row0 + r) * DM + col] = ll;
            }
        }
    }
}

// ---------------------------------------------------------------------------
extern "C" void kernel_launch(void* const* d_in, const int* in_sizes, int n_in,
                              void* d_out, int out_size, void* d_ws, size_t ws_size,
                              hipStream_t stream) {
    const float* x   = (const float*)d_in[0];
    const float* Wq  = (const float*)d_in[1];
    const float* bq  = (const float*)d_in[2];
    const float* Wk  = (const float*)d_in[3];
    const float* bk  = (const float*)d_in[4];
    const float* Wv  = (const float*)d_in[5];
    const float* bv  = (const float*)d_in[6];
    const float* Wo  = (const float*)d_in[7];
    const float* bo  = (const float*)d_in[8];
    const int* tokpos = (const int*)d_in[9];
    float* out = (float*)d_out;

    char* wsb = (char*)d_ws;
    const long NE = 4194304;                       // elems per [b,h,s,dk] array
    ushort* qh = (ushort*)wsb;                     // 6 x 8MB
    ushort* ql = qh + NE;
    ushort* kh = ql + NE;
    ushort* kl = kh + NE;
    ushort* vh = kl + NE;
    ushort* vl = vh + NE;
    ushort* wh = (ushort*)(wsb + 48ll * 1024 * 1024);   // 4 x 1M elems = 8MB
    ushort* wl = (ushort*)(wsb + 56ll * 1024 * 1024);   // 8MB
    ushort* xh = (ushort*)(wsb + 64ll * 1024 * 1024);   // 8MB (reused as attn hi)
    ushort* xl = (ushort*)(wsb + 72ll * 1024 * 1024);   // 8MB (reused as attn lo)
    float* rope_tab = (float*)(wsb + 80ll * 1024 * 1024);

    convert_kernel<<<8192, 256, 0, stream>>>(x, Wq, Wk, Wv, Wo, xh, xl, wh, wl);
    rope_table_kernel<<<256, 256, 0, stream>>>(rope_tab);

    mfma_gemm<0><<<dim3(32, 16, 3), 256, 0, stream>>>(
        xh, xl, wh, wl, bq, bk, bv, rope_tab, tokpos,
        qh, ql, kh, kl, vh, vl, nullptr);

    flash_kernel<<<dim3(16, 32), 256, 0, stream>>>(
        qh, ql, kh, kl, vh, vl, xh, xl);   // attn output aliases xh/xl (x dead)

    mfma_gemm<1><<<dim3(32, 16, 1), 256, 0, stream>>>(
        xh, xl, wh, wl, bo, nullptr, nullptr, rope_tab, tokpos,
        nullptr, nullptr, nullptr, nullptr, nullptr, nullptr, out);
}

// Round 8
// 341.613 us; speedup vs baseline: 1.4959x; 1.4959x over previous
//
#include <hip/hip_runtime.h>
#include <hip/hip_bf16.h>
#include <math.h>

#define S_LEN 2048
#define DM 1024
#define NH 16
#define DK 64

typedef short s8v __attribute__((ext_vector_type(8)));   // 8 bf16 (A/B frag, 4 VGPR)
typedef float f4v __attribute__((ext_vector_type(4)));   // 4 f32  (C/D frag)

__device__ inline ushort bf16_rn(float v) {
    unsigned u = __float_as_uint(v);
    u += 0x7FFFu + ((u >> 16) & 1u);
    return (ushort)(u >> 16);
}
__device__ inline float bf16f(ushort h) { return __uint_as_float(((unsigned)h) << 16); }

// ---------------------------------------------------------------------------
// Pre-split fp32 -> bf16 hi + lo residual for x and the 4 weight matrices.
// ---------------------------------------------------------------------------
__global__ __launch_bounds__(256) void convert_kernel(
    const float* __restrict__ x,
    const float* __restrict__ Wq, const float* __restrict__ Wk,
    const float* __restrict__ Wv, const float* __restrict__ Wo,
    ushort* __restrict__ xh, ushort* __restrict__ xl,
    ushort* __restrict__ wh, ushort* __restrict__ wl)
{
    long idx = (long)blockIdx.x * 256 + threadIdx.x;    // 2M float4 groups
    const float4* src;
    ushort* dh; ushort* dl; long off;
    if (idx < 1048576) {                                 // x: 4M elems
        src = (const float4*)x; off = idx; dh = xh; dl = xl;
    } else {
        long wi = idx - 1048576;
        int which = (int)(wi >> 18);                     // 262144 groups per W
        const float* wp = which == 0 ? Wq : which == 1 ? Wk : which == 2 ? Wv : Wo;
        src = (const float4*)wp; off = wi & 262143;
        dh = wh + (long)which * 1048576;
        dl = wl + (long)which * 1048576;
    }
    float4 v = src[off];
    ushort4 hv, lv;
    hv.x = bf16_rn(v.x); lv.x = bf16_rn(v.x - bf16f(hv.x));
    hv.y = bf16_rn(v.y); lv.y = bf16_rn(v.y - bf16f(hv.y));
    hv.z = bf16_rn(v.z); lv.z = bf16_rn(v.z - bf16f(hv.z));
    hv.w = bf16_rn(v.w); lv.w = bf16_rn(v.w - bf16f(hv.w));
    ((ushort4*)dh)[off] = hv;
    ((ushort4*)dl)[off] = lv;
}

// ---------------------------------------------------------------------------
// RoPE cos/sin table
// ---------------------------------------------------------------------------
__global__ __launch_bounds__(256) void rope_table_kernel(float* __restrict__ tab) {
    int idx = blockIdx.x * 256 + threadIdx.x;
    if (idx >= S_LEN * 32) return;
    int p = idx >> 5, i = idx & 31;
    float invf = powf(10000.0f, -(float)(2 * i) / 64.0f);
    float ang = (float)p * invf;
    tab[idx * 2 + 0] = cosf(ang);
    tab[idx * 2 + 1] = sinf(ang);
}

// ---------------------------------------------------------------------------
// Split-bf16 MFMA GEMM on pre-split inputs (unchanged from round 5).
// ---------------------------------------------------------------------------
template <int MODE>
__global__ __launch_bounds__(256, 2) void mfma_gemm(
    const ushort* __restrict__ Ah_g, const ushort* __restrict__ Al_g,
    const ushort* __restrict__ Wh_g, const ushort* __restrict__ Wl_g,
    const float* __restrict__ b0, const float* __restrict__ b1, const float* __restrict__ b2,
    const float* __restrict__ rope_tab, const int* __restrict__ tokpos,
    ushort* __restrict__ qh, ushort* __restrict__ ql,
    ushort* __restrict__ kh, ushort* __restrict__ kl,
    ushort* __restrict__ vh, ushort* __restrict__ vl,
    float* __restrict__ out)
{
    const int m0 = blockIdx.x * 128;
    const int n0 = blockIdx.y * 64;
    const int which = (MODE == 0) ? blockIdx.z : 0;
    const ushort* WhP = Wh_g + (long)(MODE == 0 ? which : 3) * 1048576;
    const ushort* WlP = Wl_g + (long)(MODE == 0 ? which : 3) * 1048576;
    const float* bias = (which == 0) ? b0 : (which == 1) ? b1 : b2;

    __shared__ ushort Ah[128 * 64], Al[128 * 64];
    __shared__ ushort Bh[64 * 64],  Bl[64 * 64];

    const int t = threadIdx.x;
    const int w = t >> 6, l = t & 63, g = l >> 4, c = l & 15;
    const int wm = w >> 1, wn = w & 1;

    const int rA2 = t >> 1;
    const int kh0 = (t & 1) * 32;
    const int rW  = t >> 2;
    const int kq0 = (t & 3) * 16;

    f4v acc[4][2];
#pragma unroll
    for (int i = 0; i < 4; ++i)
#pragma unroll
        for (int j = 0; j < 2; ++j) acc[i][j] = (f4v){0.f, 0.f, 0.f, 0.f};

    const ushort* ApH = Ah_g + (long)(m0 + rA2) * DM + kh0;
    const ushort* ApL = Al_g + (long)(m0 + rA2) * DM + kh0;
    const ushort* WpH = WhP + (long)(n0 + rW) * DM + kq0;
    const ushort* WpL = WlP + (long)(n0 + rW) * DM + kq0;

    s8v pah[4], pal[4], pwh[2], pwl[2];
#pragma unroll
    for (int q = 0; q < 4; ++q) {
        pah[q] = *(const s8v*)(ApH + q * 8);
        pal[q] = *(const s8v*)(ApL + q * 8);
    }
#pragma unroll
    for (int q = 0; q < 2; ++q) {
        pwh[q] = *(const s8v*)(WpH + q * 8);
        pwl[q] = *(const s8v*)(WpL + q * 8);
    }

    for (int ch = 0; ch < 16; ++ch) {
        __syncthreads();
#pragma unroll
        for (int q = 0; q < 4; ++q) {
            const int b = (kh0 >> 3) + q;
            const int sb = (b ^ (rA2 & 7)) * 8;
            *(s8v*)&Ah[rA2 * 64 + sb] = pah[q];
            *(s8v*)&Al[rA2 * 64 + sb] = pal[q];
        }
#pragma unroll
        for (int q = 0; q < 2; ++q) {
            const int b = (kq0 >> 3) + q;
            const int sb = (b ^ (rW & 7)) * 8;
            *(s8v*)&Bh[rW * 64 + sb] = pwh[q];
            *(s8v*)&Bl[rW * 64 + sb] = pwl[q];
        }
        __syncthreads();

        if (ch + 1 < 16) {
            const int k0 = (ch + 1) * 64;
#pragma unroll
            for (int q = 0; q < 4; ++q) {
                pah[q] = *(const s8v*)(ApH + k0 + q * 8);
                pal[q] = *(const s8v*)(ApL + k0 + q * 8);
            }
#pragma unroll
            for (int q = 0; q < 2; ++q) {
                pwh[q] = *(const s8v*)(WpH + k0 + q * 8);
                pwl[q] = *(const s8v*)(WpL + k0 + q * 8);
            }
        }

#pragma unroll
        for (int kc = 0; kc < 2; ++kc) {
            const int blk = ((kc * 4 + g) ^ (c & 7)) * 8;
            s8v afh[4], afl[4], bfh[2], bfl[2];
#pragma unroll
            for (int mf = 0; mf < 4; ++mf) {
                const int row = wm * 64 + mf * 16 + c;
                afh[mf] = *(const s8v*)&Ah[row * 64 + blk];
                afl[mf] = *(const s8v*)&Al[row * 64 + blk];
            }
#pragma unroll
            for (int nf = 0; nf < 2; ++nf) {
                const int row = wn * 32 + nf * 16 + c;
                bfh[nf] = *(const s8v*)&Bh[row * 64 + blk];
                bfl[nf] = *(const s8v*)&Bl[row * 64 + blk];
            }
#pragma unroll
            for (int mf = 0; mf < 4; ++mf)
#pragma unroll
                for (int nf = 0; nf < 2; ++nf) {
                    acc[mf][nf] = __builtin_amdgcn_mfma_f32_16x16x32_bf16(afh[mf], bfh[nf], acc[mf][nf], 0, 0, 0);
                    acc[mf][nf] = __builtin_amdgcn_mfma_f32_16x16x32_bf16(afh[mf], bfl[nf], acc[mf][nf], 0, 0, 0);
                    acc[mf][nf] = __builtin_amdgcn_mfma_f32_16x16x32_bf16(afl[mf], bfh[nf], acc[mf][nf], 0, 0, 0);
                }
        }
    }

#pragma unroll
    for (int nf = 0; nf < 2; ++nf) {
        const int ecol = n0 + wn * 32 + nf * 16 + c;
        const float bv = bias[ecol];
        if (MODE == 1) {
#pragma unroll
            for (int mf = 0; mf < 4; ++mf)
#pragma unroll
                for (int r = 0; r < 4; ++r) {
                    const int m = m0 + wm * 64 + mf * 16 + 4 * g + r;
                    out[(long)m * DM + ecol] = acc[mf][nf][r] + bv;
                }
        } else {
            const int hH = ecol >> 6, dk = ecol & 63, fi = dk >> 1;
            ushort* dh = (which == 0) ? qh : (which == 1) ? kh : vh;
            ushort* dl = (which == 0) ? ql : (which == 1) ? kl : vl;
#pragma unroll
            for (int mf = 0; mf < 4; ++mf)
#pragma unroll
                for (int r = 0; r < 4; ++r) {
                    const int m = m0 + wm * 64 + mf * 16 + 4 * g + r;
                    const float val = acc[mf][nf][r] + bv;
                    const float par = __shfl_xor(val, 1);
                    float vr;
                    if (which == 2) {
                        vr = val;
                    } else {
                        const int pos = tokpos[m];
                        const float2 cs = ((const float2*)rope_tab)[pos * 32 + fi];
                        vr = (c & 1) ? fmaf(par, cs.y, val * cs.x)
                                     : fmaf(val, cs.x, -par * cs.y);
                    }
                    const ushort hh = bf16_rn(vr);
                    const ushort ll = bf16_rn(vr - bf16f(hh));
                    const long base = ((long)((m >> 11) * NH + hH) * S_LEN + (m & (S_LEN - 1))) * DK + dk;
                    dh[base] = hh;
                    dl[base] = ll;
                }
        }
    }
}

// ---------------------------------------------------------------------------
// Split-bf16 MFMA flash attention, causal, swapped QK^T, balanced q-pairing.
// ROUND-5 STRUCTURE (dual per-wave P buffers, stride-64 verified swizzle,
// launch_bounds(256,2), ~120 VGPR no-spill) with ONLY the pairing changed:
//   p_ = blockIdx.x>>1, half = blockIdx.x&1
//   qf=1 (heavy): q-rows (15-p_)*128 + half*64 + w*16 .. +16
//   qf=0 (light): q-rows  p_   *128 + half*64 + w*16 .. +16
// ntiles = 2*(15-p_)+half+1; per-block cost spread ~1.35x (was 32x).
// S^T = K*Q^T per qf; K-frags and V-frags shared across both qf.
// P (bf16 hi/lo, packed u32) in per-wave-private LDS; no barriers around it.
// LDS = 32KB (K/V) + 32KB (P) = 64KB -> 2 blocks/CU.
// ---------------------------------------------------------------------------
__global__ __launch_bounds__(256, 2) void flash_kernel(
    const ushort* __restrict__ qh_g, const ushort* __restrict__ ql_g,
    const ushort* __restrict__ kh_g, const ushort* __restrict__ kl_g,
    const ushort* __restrict__ vh_g, const ushort* __restrict__ vl_g,
    ushort* __restrict__ ah_g, ushort* __restrict__ al_g)
{
    const int bh = blockIdx.y;
    const int p_ = (int)blockIdx.x >> 1;      // 0..7 (heavy blocks dispatch first)
    const int half = (int)blockIdx.x & 1;
    const int qb_hi = 15 - p_;                // 8..15
    const int qb_lo = p_;                     // 0..7
    const int t = threadIdx.x;
    const int w = t >> 6, l = t & 63, g = l >> 4, c = l & 15;
    const int h = bh & (NH - 1), b_idx = bh >> 4;

    int qbase[2];
    qbase[0] = qb_lo * 128 + half * 64 + w * 16;
    qbase[1] = qb_hi * 128 + half * 64 + w * 16;
    const int ntiles = 2 * qb_hi + half + 1;

    __shared__ ushort Kh[64 * 64], Kl[64 * 64];   // [kv][d] swizzled, 8KB each
    __shared__ ushort Vh[64 * 64], Vl[64 * 64];   // [d][kv] swizzled
    __shared__ uint P_[8192];                      // [wave][qf][q16][hl][32 u32]
    uint* Pw = P_ + (w * 2) * 1024;

    // Q B-frags (col=q=c, k=d)
    s8v qhf[2][2], qlf[2][2];
#pragma unroll
    for (int qf = 0; qf < 2; ++qf)
#pragma unroll
        for (int kc = 0; kc < 2; ++kc) {
            const long base = ((long)bh * S_LEN + qbase[qf] + c) * DK + kc * 32 + g * 8;
            qhf[qf][kc] = *(const s8v*)(qh_g + base);
            qlf[qf][kc] = *(const s8v*)(ql_g + base);
        }

    f4v o[2][4];
#pragma unroll
    for (int qf = 0; qf < 2; ++qf)
#pragma unroll
        for (int nt = 0; nt < 4; ++nt) o[qf][nt] = (f4v){0.f, 0.f, 0.f, 0.f};
    float m_[2] = {-INFINITY, -INFINITY};
    float l_[2] = {0.f, 0.f};

    // register prefetch of tile 0
    s8v pkh[2], pkl[2], pvh[2], pvl[2];
    {
        const long rb = ((long)bh * S_LEN + l) * DK;
#pragma unroll
        for (int ib = 0; ib < 2; ++ib) {
            const int b = w + ib * 4;
            pkh[ib] = *(const s8v*)(kh_g + rb + b * 8);
            pkl[ib] = *(const s8v*)(kl_g + rb + b * 8);
            pvh[ib] = *(const s8v*)(vh_g + rb + b * 8);
            pvl[ib] = *(const s8v*)(vl_g + rb + b * 8);
        }
    }

    for (int tile = 0; tile < ntiles; ++tile) {
        __syncthreads();   // prev compute done reading K/V LDS

        // ---- commit K (b128) + V transposed (lane-pair b32) ----
#pragma unroll
        for (int ib = 0; ib < 2; ++ib) {
            const int b = w + ib * 4;
            const int sb = b ^ (l & 7);
            *(s8v*)&Kh[l * 64 + sb * 8] = pkh[ib];
            *(s8v*)&Kl[l * 64 + sb * 8] = pkl[ib];

            uint4 uh = *(uint4*)&pvh[ib];
            uint4 ul = *(uint4*)&pvl[ib];
            uint4 ph_, pl_;
            ph_.x = (uint)__shfl_xor((int)uh.x, 1); ph_.y = (uint)__shfl_xor((int)uh.y, 1);
            ph_.z = (uint)__shfl_xor((int)uh.z, 1); ph_.w = (uint)__shfl_xor((int)uh.w, 1);
            pl_.x = (uint)__shfl_xor((int)ul.x, 1); pl_.y = (uint)__shfl_xor((int)ul.y, 1);
            pl_.z = (uint)__shfl_xor((int)ul.z, 1); pl_.w = (uint)__shfl_xor((int)ul.w, 1);
            const int colp = l & ~1;
            const int odd  = l & 1;
#pragma unroll
            for (int j = 0; j < 4; ++j) {
                const ushort oj   = ((const ushort*)&uh)[j];
                const ushort oj4  = ((const ushort*)&uh)[j + 4];
                const ushort pj   = ((const ushort*)&ph_)[j];
                const ushort pj4  = ((const ushort*)&ph_)[j + 4];
                const ushort loj  = ((const ushort*)&ul)[j];
                const ushort loj4 = ((const ushort*)&ul)[j + 4];
                const ushort plj  = ((const ushort*)&pl_)[j];
                const ushort plj4 = ((const ushort*)&pl_)[j + 4];
                const int d   = b * 8 + (odd ? 4 + j : j);
                const uint hv = odd ? ((uint)pj4  | ((uint)oj4  << 16))
                                    : ((uint)oj   | ((uint)pj   << 16));
                const uint lv = odd ? ((uint)plj4 | ((uint)loj4 << 16))
                                    : ((uint)loj  | ((uint)plj  << 16));
                const int sc2 = (colp >> 3) ^ (d & 7);
                *(uint*)&Vh[d * 64 + sc2 * 8 + (colp & 7)] = hv;
                *(uint*)&Vl[d * 64 + sc2 * 8 + (colp & 7)] = lv;
            }
        }
        __syncthreads();

        // ---- prefetch next tile (hides under compute) ----
        if (tile + 1 < ntiles) {
            const long rb = ((long)bh * S_LEN + (tile + 1) * 64 + l) * DK;
#pragma unroll
            for (int ib = 0; ib < 2; ++ib) {
                const int b = w + ib * 4;
                pkh[ib] = *(const s8v*)(kh_g + rb + b * 8);
                pkl[ib] = *(const s8v*)(kl_g + rb + b * 8);
                pvh[ib] = *(const s8v*)(vh_g + rb + b * 8);
                pvl[ib] = *(const s8v*)(vl_g + rb + b * 8);
            }
        }

        const int kvbase = tile * 64;
        int nt_hi[2];
#pragma unroll
        for (int qf = 0; qf < 2; ++qf) {
            const int lim = qbase[qf] + 15 - kvbase;
            int v = lim < 0 ? 0 : (lim >> 4) + 1;
            nt_hi[qf] = v > 4 ? 4 : v;
        }

        // ---- S^T = K * Q^T (3-pass split); K-frag shared across qf ----
        f4v sc[2][4];
#pragma unroll
        for (int qf = 0; qf < 2; ++qf)
#pragma unroll
            for (int nt = 0; nt < 4; ++nt) sc[qf][nt] = (f4v){0.f, 0.f, 0.f, 0.f};
#pragma unroll
        for (int nt = 0; nt < 4; ++nt) {
            if (nt >= nt_hi[1]) continue;              // nt_hi[1] >= nt_hi[0]
            const int kvl = nt * 16 + c;
#pragma unroll
            for (int kc = 0; kc < 2; ++kc) {
                const int blk = ((kc * 4 + g) ^ (c & 7)) * 8;
                s8v kfh = *(const s8v*)&Kh[kvl * 64 + blk];
                s8v kfl = *(const s8v*)&Kl[kvl * 64 + blk];
#pragma unroll
                for (int qf = 0; qf < 2; ++qf) {
                    if (nt >= nt_hi[qf]) continue;
                    sc[qf][nt] = __builtin_amdgcn_mfma_f32_16x16x32_bf16(kfh, qhf[qf][kc], sc[qf][nt], 0, 0, 0);
                    sc[qf][nt] = __builtin_amdgcn_mfma_f32_16x16x32_bf16(kfh, qlf[qf][kc], sc[qf][nt], 0, 0, 0);
                    sc[qf][nt] = __builtin_amdgcn_mfma_f32_16x16x32_bf16(kfl, qhf[qf][kc], sc[qf][nt], 0, 0, 0);
                }
            }
        }

        // ---- softmax (row q=c in-lane) + packed P write + O rescale ----
#pragma unroll
        for (int qf = 0; qf < 2; ++qf) {
            if (nt_hi[qf] == 0) continue;
            const bool needMask = (kvbase + 63) > qbase[qf];
            float s_[4][4];
#pragma unroll
            for (int nt = 0; nt < 4; ++nt)
#pragma unroll
                for (int r = 0; r < 4; ++r) {
                    const float v = sc[qf][nt][r] * 0.125f;
                    const bool bad = (nt >= nt_hi[qf]) ||
                        (needMask && (kvbase + 16 * nt + 4 * g + r > qbase[qf] + c));
                    s_[nt][r] = bad ? -INFINITY : v;
                }
            float tm = -INFINITY;
#pragma unroll
            for (int nt = 0; nt < 4; ++nt)
#pragma unroll
                for (int r = 0; r < 4; ++r) tm = fmaxf(tm, s_[nt][r]);
            tm = fmaxf(tm, __shfl_xor(tm, 16));
            tm = fmaxf(tm, __shfl_xor(tm, 32));
            const float mnew = fmaxf(m_[qf], tm);
            const float corr = __expf(m_[qf] - mnew);
            uint* Pq = Pw + qf * 1024 + c * 64;
            float psum = 0.f;
#pragma unroll
            for (int nt = 0; nt < 4; ++nt) {
                const float p0 = __expf(s_[nt][0] - mnew);
                const float p1 = __expf(s_[nt][1] - mnew);
                const float p2 = __expf(s_[nt][2] - mnew);
                const float p3 = __expf(s_[nt][3] - mnew);
                psum += (p0 + p1) + (p2 + p3);
                const ushort h0 = bf16_rn(p0), h1 = bf16_rn(p1);
                const ushort h2 = bf16_rn(p2), h3 = bf16_rn(p3);
                const ushort e0 = bf16_rn(p0 - bf16f(h0)), e1 = bf16_rn(p1 - bf16f(h1));
                const ushort e2 = bf16_rn(p2 - bf16f(h2)), e3 = bf16_rn(p3 - bf16f(h3));
                const int u0 = ((2 * nt + (g >> 1)) ^ (c & 7)) * 4 + 2 * (g & 1);
                uint2 hw; hw.x = (uint)h0 | ((uint)h1 << 16); hw.y = (uint)h2 | ((uint)h3 << 16);
                uint2 lw; lw.x = (uint)e0 | ((uint)e1 << 16); lw.y = (uint)e2 | ((uint)e3 << 16);
                *(uint2*)(Pq + u0) = hw;
                *(uint2*)(Pq + 32 + u0) = lw;
            }
            psum += __shfl_xor(psum, 16);
            psum += __shfl_xor(psum, 32);
            l_[qf] = l_[qf] * corr + psum;
            m_[qf] = mnew;
            // redistribute corr to O-row holders (row q = 4g+r)
            float cD0 = __shfl(corr, (l & 48) + 4 * g + 0);
            float cD1 = __shfl(corr, (l & 48) + 4 * g + 1);
            float cD2 = __shfl(corr, (l & 48) + 4 * g + 2);
            float cD3 = __shfl(corr, (l & 48) + 4 * g + 3);
#pragma unroll
            for (int nt = 0; nt < 4; ++nt) {
                o[qf][nt][0] *= cD0; o[qf][nt][1] *= cD1;
                o[qf][nt][2] *= cD2; o[qf][nt][3] *= cD3;
            }
        }

        // ---- PV (3-pass split); V-frags shared across qf ----
#pragma unroll
        for (int kc = 0; kc < 2; ++kc) {
            if (nt_hi[1] <= kc * 2) continue;
            const bool q0go = nt_hi[0] > kc * 2;
            const int pswz = ((4 * kc + g) ^ (c & 7)) * 4;
            s8v pa1h = *(const s8v*)(Pw + 1024 + c * 64 + pswz);
            s8v pa1l = *(const s8v*)(Pw + 1024 + c * 64 + 32 + pswz);
            s8v pa0h, pa0l;
            if (q0go) {
                pa0h = *(const s8v*)(Pw + c * 64 + pswz);
                pa0l = *(const s8v*)(Pw + c * 64 + 32 + pswz);
            }
#pragma unroll
            for (int nt = 0; nt < 4; ++nt) {
                const int dcol = nt * 16 + c;
                const int vblk = ((kc * 4 + g) ^ (c & 7)) * 8;
                s8v vfh = *(const s8v*)&Vh[dcol * 64 + vblk];
                s8v vfl = *(const s8v*)&Vl[dcol * 64 + vblk];
                o[1][nt] = __builtin_amdgcn_mfma_f32_16x16x32_bf16(pa1h, vfh, o[1][nt], 0, 0, 0);
                o[1][nt] = __builtin_amdgcn_mfma_f32_16x16x32_bf16(pa1h, vfl, o[1][nt], 0, 0, 0);
                o[1][nt] = __builtin_amdgcn_mfma_f32_16x16x32_bf16(pa1l, vfh, o[1][nt], 0, 0, 0);
                if (q0go) {
                    o[0][nt] = __builtin_amdgcn_mfma_f32_16x16x32_bf16(pa0h, vfh, o[0][nt], 0, 0, 0);
                    o[0][nt] = __builtin_amdgcn_mfma_f32_16x16x32_bf16(pa0h, vfl, o[0][nt], 0, 0, 0);
                    o[0][nt] = __builtin_amdgcn_mfma_f32_16x16x32_bf16(pa0l, vfh, o[0][nt], 0, 0, 0);
                }
            }
        }
    }

    // ---- epilogue: normalize (inv redistributed), split-store bf16 hi/lo ----
#pragma unroll
    for (int qf = 0; qf < 2; ++qf) {
        const float inv = 1.0f / l_[qf];
        float iD0 = __shfl(inv, (l & 48) + 4 * g + 0);
        float iD1 = __shfl(inv, (l & 48) + 4 * g + 1);
        float iD2 = __shfl(inv, (l & 48) + 4 * g + 2);
        float iD3 = __shfl(inv, (l & 48) + 4 * g + 3);
#pragma unroll
        for (int nt = 0; nt < 4; ++nt) {
            float vv[4];
            vv[0] = o[qf][nt][0] * iD0;
            vv[1] = o[qf][nt][1] * iD1;
            vv[2] = o[qf][nt][2] * iD2;
            vv[3] = o[qf][nt][3] * iD3;
            const long row0 = (long)b_idx * S_LEN + qbase[qf] + 4 * g;
            const long col = h * DK + nt * 16 + c;
#pragma unroll
            for (int r = 0; r < 4; ++r) {
                const ushort hh = bf16_rn(vv[r]);
                const ushort ll = bf16_rn(vv[r] - bf16f(hh));
                ah_g[(row0 + r) * DM + col] = hh;
                al_g[(row0 + r) * DM + col] = ll;
            }
        }
    }
}

// ---------------------------------------------------------------------------
extern "C" void kernel_launch(void* const* d_in, const int* in_sizes, int n_in,
                              void* d_out, int out_size, void* d_ws, size_t ws_size,
                              hipStream_t stream) {
    const float* x   = (const float*)d_in[0];
    const float* Wq  = (const float*)d_in[1];
    const float* bq  = (const float*)d_in[2];
    const float* Wk  = (const float*)d_in[3];
    const float* bk  = (const float*)d_in[4];
    const float* Wv  = (const float*)d_in[5];
    const float* bv  = (const float*)d_in[6];
    const float* Wo  = (const float*)d_in[7];
    const float* bo  = (const float*)d_in[8];
    const int* tokpos = (const int*)d_in[9];
    float* out = (float*)d_out;

    char* wsb = (char*)d_ws;
    const long NE = 4194304;                       // elems per [b,h,s,dk] array
    ushort* qh = (ushort*)wsb;                     // 6 x 8MB
    ushort* ql = qh + NE;
    ushort* kh = ql + NE;
    ushort* kl = kh + NE;
    ushort* vh = kl + NE;
    ushort* vl = vh + NE;
    ushort* wh = (ushort*)(wsb + 48ll * 1024 * 1024);   // 4 x 1M elems = 8MB
    ushort* wl = (ushort*)(wsb + 56ll * 1024 * 1024);   // 8MB
    ushort* xh = (ushort*)(wsb + 64ll * 1024 * 1024);   // 8MB (reused as attn hi)
    ushort* xl = (ushort*)(wsb + 72ll * 1024 * 1024);   // 8MB (reused as attn lo)
    float* rope_tab = (float*)(wsb + 80ll * 1024 * 1024);

    convert_kernel<<<8192, 256, 0, stream>>>(x, Wq, Wk, Wv, Wo, xh, xl, wh, wl);
    rope_table_kernel<<<256, 256, 0, stream>>>(rope_tab);

    mfma_gemm<0><<<dim3(32, 16, 3), 256, 0, stream>>>(
        xh, xl, wh, wl, bq, bk, bv, rope_tab, tokpos,
        qh, ql, kh, kl, vh, vl, nullptr);

    flash_kernel<<<dim3(16, 32), 256, 0, stream>>>(
        qh, ql, kh, kl, vh, vl, xh, xl);   // attn output aliases xh/xl (x dead)

    mfma_gemm<1><<<dim3(32, 16, 1), 256, 0, stream>>>(
        xh, xl, wh, wl, bo, nullptr, nullptr, rope_tab, tokpos,
        nullptr, nullptr, nullptr, nullptr, nullptr, nullptr, out);
}